// Round 1
// baseline (97142.102 us; speedup 1.0000x reference)
//
#include <hip/hip_runtime.h>
#include <hip/hip_cooperative_groups.h>
#include <math.h>

// ESN forward: x_{t+1} = 0.1*x_t + 0.9*tanh(W_in @ u_t + W @ x_t); y_t = Wout @ x_{t+1}
// W sparse (5%) -> padded ELL in ws; cooperative kernel, 64 WGs, 1 grid.sync per step.

#define NX 4096
#define NU 128
#define NY 64
#define TSTEPS 4096
#define CAP 352            // padded nnz per row (mean 204.8, sd 13.9 -> 352 is >10 sigma)
#define WGS 64
#define TPB 512
#define RPW (NX / WGS)     // 64 rows per workgroup
#define TPR (TPB / RPW)    // 8 threads per row
#define EPT (CAP / TPR)    // 44 ELL entries per thread
#define UPT (NU / TPR)     // 16 W_in entries per thread

namespace cg = cooperative_groups;

// --- Kernel 1: deterministic dense->ELL compaction, one block per row ---
__global__ void build_ell_kernel(const float* __restrict__ W, int2* __restrict__ ell) {
    const int r = blockIdx.x;
    const int tid = threadIdx.x;
    const int wv = tid >> 6, ln = tid & 63;
    __shared__ int wave_tot[4];
    __shared__ int base;
    if (tid == 0) base = 0;
    __syncthreads();
    const float* row = W + (size_t)r * NX;
    int2* out = ell + (size_t)r * CAP;
    for (int chunk = 0; chunk < NX; chunk += 256) {
        float w = row[chunk + tid];
        bool p = (w != 0.0f);
        unsigned long long m = __ballot(p);
        int lp = (int)__popcll(m & ((1ull << ln) - 1ull));
        if (ln == 63) wave_tot[wv] = lp + (p ? 1 : 0);
        __syncthreads();
        int wbase = 0;
        #pragma unroll
        for (int i = 0; i < 4; ++i)
            if (i < wv) wbase += wave_tot[i];
        int tot = wave_tot[0] + wave_tot[1] + wave_tot[2] + wave_tot[3];
        if (p) {
            int o = base + wbase + lp;
            if (o < CAP) out[o] = make_int2(chunk + tid, __float_as_int(w));
        }
        __syncthreads();
        if (tid == 0) base += tot;
        __syncthreads();
    }
    // zero-pad remainder: col=0, val=0 contributes exactly 0 to the dot product
    for (int o = base + tid; o < CAP; o += 256) out[o] = make_int2(0, 0);
}

// --- Kernel 2: cooperative sequential recurrence ---
__global__ void __launch_bounds__(TPB, 1) esn_kernel(
    const float* __restrict__ UT, const float* __restrict__ x0,
    const float* __restrict__ Win, const float* __restrict__ Wout,
    const int2* __restrict__ ell, float* __restrict__ xbuf,  // [2][NX]
    float* __restrict__ Y)
{
    cg::grid_group grid = cg::this_grid();

    __shared__ __align__(16) float xl[NX];   // full state, indexed by global col
    __shared__ float ul[NU];
    __shared__ float red[TPB / 64];

    const int tid = threadIdx.x;
    const int wg  = blockIdx.x;              // 0..63
    const int grp = tid >> 3;                // row group within WG (0..63)
    const int ln  = tid & 7;                 // lane within row group
    const int r   = wg * RPW + grp;          // global row this 8-thread group owns

    const float* winrow  = Win  + (size_t)r  * NU;
    const int2*  ellrow  = ell  + (size_t)r  * CAP;
    const float* woutrow = Wout + (size_t)wg * NX;

    for (int t = 0; t < TSTEPS; ++t) {
        const float* xsrc = (t == 0) ? x0 : (xbuf + (size_t)(t & 1) * NX);
        // stage x_t and u_t into LDS (vectorized)
        const float4* xs4 = (const float4*)xsrc;
        float4* xl4 = (float4*)xl;
        #pragma unroll
        for (int i = tid; i < NX / 4; i += TPB) xl4[i] = xs4[i];
        if (tid < NU) ul[tid] = UT[(size_t)t * NU + tid];
        __syncthreads();

        // readout for previous step: Y[t-1][wg] = Wout[wg] . x_t
        if (t > 0) {
            float a = 0.0f;
            for (int i = tid; i < NX; i += TPB) a += woutrow[i] * xl[i];
            for (int off = 32; off; off >>= 1) a += __shfl_down(a, off, 64);
            if ((tid & 63) == 0) red[tid >> 6] = a;
            __syncthreads();
            if (tid == 0) {
                float s = 0.0f;
                #pragma unroll
                for (int i = 0; i < TPB / 64; ++i) s += red[i];
                Y[(size_t)(t - 1) * NY + wg] = s;
            }
        }

        // pre[r] = Win[r,:] @ u  +  W[r,:] @ x  (sparse ELL)
        float acc = 0.0f;
        #pragma unroll
        for (int i = 0; i < UPT; ++i) {
            int k = ln + TPR * i;
            acc += winrow[k] * ul[k];
        }
        #pragma unroll 4
        for (int i = 0; i < EPT; ++i) {
            int2 cv = ellrow[ln + TPR * i];
            acc += __int_as_float(cv.y) * xl[cv.x];
        }
        acc += __shfl_down(acc, 4, 8);
        acc += __shfl_down(acc, 2, 8);
        acc += __shfl_down(acc, 1, 8);
        if (ln == 0) {
            float xn = 0.1f * xl[r] + 0.9f * tanhf(acc);
            xbuf[(size_t)((t + 1) & 1) * NX + r] = xn;
        }
        __threadfence();   // device-scope release of x_{t+1} before the barrier
        grid.sync();
    }

    // final readout: Y[T-1][wg] = Wout[wg] . x_T   (x_T in xbuf[(T&1)*NX])
    {
        const float* xs = xbuf + (size_t)(TSTEPS & 1) * NX;
        float a = 0.0f;
        for (int i = tid; i < NX; i += TPB) a += woutrow[i] * xs[i];
        for (int off = 32; off; off >>= 1) a += __shfl_down(a, off, 64);
        if ((tid & 63) == 0) red[tid >> 6] = a;
        __syncthreads();
        if (tid == 0) {
            float s = 0.0f;
            #pragma unroll
            for (int i = 0; i < TPB / 64; ++i) s += red[i];
            Y[(size_t)(TSTEPS - 1) * NY + wg] = s;
        }
    }
}

extern "C" void kernel_launch(void* const* d_in, const int* in_sizes, int n_in,
                              void* d_out, int out_size, void* d_ws, size_t ws_size,
                              hipStream_t stream) {
    const float* UT   = (const float*)d_in[0];  // [T, NU]
    const float* x0   = (const float*)d_in[1];  // [NX]
    const float* Win  = (const float*)d_in[2];  // [NX, NU]
    const float* W    = (const float*)d_in[3];  // [NX, NX]
    const float* Wout = (const float*)d_in[4];  // [NY, NX]
    float* Y = (float*)d_out;                   // [T*NY]

    char* ws = (char*)d_ws;
    float* xbuf = (float*)ws;                   // 2*NX floats = 32 KB
    int2*  ell  = (int2*)(ws + 32768);          // NX*CAP*8 = 11.5 MB

    build_ell_kernel<<<dim3(NX), dim3(256), 0, stream>>>(W, ell);

    void* args[] = { (void*)&UT, (void*)&x0, (void*)&Win, (void*)&Wout,
                     (void*)&ell, (void*)&xbuf, (void*)&Y };
    hipLaunchCooperativeKernel((const void*)esn_kernel, dim3(WGS), dim3(TPB),
                               args, 0, stream);
}

// Round 2
// 95106.323 us; speedup vs baseline: 1.0214x; 1.0214x over previous
//
#include <hip/hip_runtime.h>
#include <math.h>

// ESN forward: x_{t+1} = 0.1*x_t + 0.9*tanh(W_in @ u_t + W @ x_t); y_t = Wout @ x_{t+1}
// W sparse (5%) -> padded ELL in ws. Cooperative-launched 64 WGs; custom
// flag-vector grid barrier (no contended atomics): WG i stores epoch to
// flags[i], wave 0 polls all 64 flags with one coalesced load + ballot.

#define NX 4096
#define NU 128
#define NY 64
#define TSTEPS 4096
#define CAP 352            // padded nnz per row (mean 204.8, sd 13.9)
#define WGS 64
#define TPB 512
#define RPW (NX / WGS)     // 64 rows per workgroup
#define TPR (TPB / RPW)    // 8 threads per row
#define EPT (CAP / TPR)    // 44 ELL entries per thread (contiguous chunk)
#define UPT (NU / TPR)     // 16 W_in entries per thread (contiguous chunk)

// --- Kernel 1: deterministic dense->ELL compaction, one block per row ---
__global__ void build_ell_kernel(const float* __restrict__ W, int2* __restrict__ ell,
                                 int* __restrict__ flags) {
    const int r = blockIdx.x;
    const int tid = threadIdx.x;
    if (r == 0 && tid < WGS) flags[tid] = 0;   // zero barrier flags for main kernel
    const int wv = tid >> 6, ln = tid & 63;
    __shared__ int wave_tot[4];
    __shared__ int base;
    if (tid == 0) base = 0;
    __syncthreads();
    const float* row = W + (size_t)r * NX;
    int2* out = ell + (size_t)r * CAP;
    for (int chunk = 0; chunk < NX; chunk += 256) {
        float w = row[chunk + tid];
        bool p = (w != 0.0f);
        unsigned long long m = __ballot(p);
        int lp = (int)__popcll(m & ((1ull << ln) - 1ull));
        if (ln == 63) wave_tot[wv] = lp + (p ? 1 : 0);
        __syncthreads();
        int wbase = 0;
        #pragma unroll
        for (int i = 0; i < 4; ++i)
            if (i < wv) wbase += wave_tot[i];
        int tot = wave_tot[0] + wave_tot[1] + wave_tot[2] + wave_tot[3];
        if (p) {
            int o = base + wbase + lp;
            if (o < CAP) out[o] = make_int2(chunk + tid, __float_as_int(w));
        }
        __syncthreads();
        if (tid == 0) base += tot;
        __syncthreads();
    }
    // zero-pad remainder: col=0, val=0 contributes exactly 0
    for (int o = base + tid; o < CAP; o += 256) out[o] = make_int2(0, 0);
}

// --- Kernel 2: cooperative sequential recurrence with flag-vector barrier ---
__global__ void __launch_bounds__(TPB, 1) esn_kernel(
    const float* __restrict__ UT, const float* __restrict__ x0,
    const float* __restrict__ Win, const float* __restrict__ Wout,
    const int2* __restrict__ ell, float* __restrict__ xbuf,  // [2][NX]
    int* __restrict__ flags, float* __restrict__ Y)
{
    __shared__ __align__(16) float xl[NX];
    __shared__ float ul[NU];
    __shared__ float red[TPB / 64];

    const int tid = threadIdx.x;
    const int wg  = blockIdx.x;              // 0..63
    const int grp = tid >> 3;                // row group within WG (0..63)
    const int ln  = tid & 7;                 // lane within row group
    const int r   = wg * RPW + grp;          // global row this 8-thread group owns

    // contiguous per-thread slices -> int4/float4 loads
    const float4* winrow = (const float4*)(Win + (size_t)r * NU + ln * UPT);
    const int4*   ellrow = (const int4*)  (ell + (size_t)r * CAP + ln * EPT);
    const float*  woutrow = Wout + (size_t)wg * NX;

    for (int t = 0; t < TSTEPS; ++t) {
        const float* xsrc = (t == 0) ? x0 : (xbuf + (size_t)(t & 1) * NX);
        const float4* xs4 = (const float4*)xsrc;
        float4* xl4 = (float4*)xl;
        #pragma unroll
        for (int i = tid; i < NX / 4; i += TPB) xl4[i] = xs4[i];
        if (tid < NU) ul[tid] = UT[(size_t)t * NU + tid];
        __syncthreads();

        // readout for previous step: Y[t-1][wg] = Wout[wg] . x_t
        if (t > 0) {
            float a = 0.0f;
            for (int i = tid; i < NX; i += TPB) a += woutrow[i] * xl[i];
            for (int off = 32; off; off >>= 1) a += __shfl_down(a, off, 64);
            if ((tid & 63) == 0) red[tid >> 6] = a;
            __syncthreads();
            if (tid == 0) {
                float s = 0.0f;
                #pragma unroll
                for (int i = 0; i < TPB / 64; ++i) s += red[i];
                Y[(size_t)(t - 1) * NY + wg] = s;
            }
        }

        // pre[r] = Win[r,:] @ u  +  W[r,:] @ x  (sparse ELL, contiguous chunks)
        float acc = 0.0f;
        const float* up = ul + ln * UPT;
        #pragma unroll
        for (int i = 0; i < UPT / 4; ++i) {
            float4 w = winrow[i];
            acc += w.x * up[4 * i] + w.y * up[4 * i + 1]
                 + w.z * up[4 * i + 2] + w.w * up[4 * i + 3];
        }
        #pragma unroll 4
        for (int i = 0; i < EPT / 2; ++i) {
            int4 cv = ellrow[i];   // two (col,val) pairs
            acc += __int_as_float(cv.y) * xl[cv.x]
                 + __int_as_float(cv.w) * xl[cv.z];
        }
        acc += __shfl_down(acc, 4, 8);
        acc += __shfl_down(acc, 2, 8);
        acc += __shfl_down(acc, 1, 8);
        if (ln == 0) {
            xbuf[(size_t)((t + 1) & 1) * NX + r] = 0.1f * xl[r] + 0.9f * tanhf(acc);
        }

        // ---- flag-vector grid barrier (release / arrive / poll / acquire) ----
        __threadfence();                       // release this thread's x-writes
        __syncthreads();                       // all WG writes fenced before signal
        if (tid == 0)
            __hip_atomic_store(flags + wg, t + 1, __ATOMIC_RELAXED,
                               __HIP_MEMORY_SCOPE_AGENT);
        if (tid < 64) {                        // wave 0 polls all 64 flags at once
            int v;
            do {
                v = __hip_atomic_load(flags + tid, __ATOMIC_RELAXED,
                                      __HIP_MEMORY_SCOPE_AGENT);
            } while (__ballot(v < t + 1) != 0ull);
        }
        __syncthreads();
        __threadfence();                       // acquire: invalidate stale lines
    }

    // final readout: Y[T-1][wg] = Wout[wg] . x_T
    {
        const float* xs = xbuf + (size_t)(TSTEPS & 1) * NX;
        float a = 0.0f;
        for (int i = tid; i < NX; i += TPB) a += woutrow[i] * xs[i];
        for (int off = 32; off; off >>= 1) a += __shfl_down(a, off, 64);
        if ((tid & 63) == 0) red[tid >> 6] = a;
        __syncthreads();
        if (tid == 0) {
            float s = 0.0f;
            #pragma unroll
            for (int i = 0; i < TPB / 64; ++i) s += red[i];
            Y[(size_t)(TSTEPS - 1) * NY + wg] = s;
        }
    }
}

extern "C" void kernel_launch(void* const* d_in, const int* in_sizes, int n_in,
                              void* d_out, int out_size, void* d_ws, size_t ws_size,
                              hipStream_t stream) {
    const float* UT   = (const float*)d_in[0];  // [T, NU]
    const float* x0   = (const float*)d_in[1];  // [NX]
    const float* Win  = (const float*)d_in[2];  // [NX, NU]
    const float* W    = (const float*)d_in[3];  // [NX, NX]
    const float* Wout = (const float*)d_in[4];  // [NY, NX]
    float* Y = (float*)d_out;                   // [T*NY]

    char* ws = (char*)d_ws;
    float* xbuf = (float*)ws;                               // 2*NX floats = 32 KB
    int2*  ell  = (int2*)(ws + 32768);                      // NX*CAP*8 = 11,534,336 B
    int*   flags = (int*)(ws + 32768 + (size_t)NX * CAP * 8);  // 64 ints

    build_ell_kernel<<<dim3(NX), dim3(256), 0, stream>>>(W, ell, flags);

    void* args[] = { (void*)&UT, (void*)&x0, (void*)&Win, (void*)&Wout,
                     (void*)&ell, (void*)&xbuf, (void*)&flags, (void*)&Y };
    hipLaunchCooperativeKernel((const void*)esn_kernel, dim3(WGS), dim3(TPB),
                               args, 0, stream);
}

// Round 3
// 24884.947 us; speedup vs baseline: 3.9036x; 3.8218x over previous
//
#include <hip/hip_runtime.h>
#include <math.h>

// ESN forward: x_{t+1} = 0.1*x_t + 0.9*tanh(W_in @ u_t + W @ x_t); y_t = Wout @ x_{t+1}
// W sparse (5%) -> padded ELL in ws. 64 cooperative WGs.
// KEY (R3): no __threadfence / no agent fences at all. Cross-step data (xbuf,
// flags) uses agent-scope relaxed atomics => sc1 L2-bypassing accesses that
// are coherent at L3 by construction. Static data (ELL/Win/Wout/UT) stays
// cached in L1/L2 forever (no invalidates). Writer orders x-stores before its
// flag store with an in-wave s_waitcnt vmcnt(0).

#define NX 4096
#define NU 128
#define NY 64
#define TSTEPS 4096
#define CAP 352            // padded nnz per row (mean 204.8, sd 13.9)
#define WGS 64
#define TPB 512
#define RPW (NX / WGS)     // 64 rows per workgroup
#define TPR (TPB / RPW)    // 8 threads per row
#define EPT (CAP / TPR)    // 44 ELL entries per thread (contiguous chunk)
#define UPT (NU / TPR)     // 16 W_in entries per thread (contiguous chunk)

// --- Kernel 1: deterministic dense->ELL compaction, one block per row ---
__global__ void build_ell_kernel(const float* __restrict__ W, int2* __restrict__ ell,
                                 int* __restrict__ flags) {
    const int r = blockIdx.x;
    const int tid = threadIdx.x;
    if (r == 0 && tid < WGS) flags[tid] = 0;   // zero barrier flags for main kernel
    const int wv = tid >> 6, ln = tid & 63;
    __shared__ int wave_tot[4];
    __shared__ int base;
    if (tid == 0) base = 0;
    __syncthreads();
    const float* row = W + (size_t)r * NX;
    int2* out = ell + (size_t)r * CAP;
    for (int chunk = 0; chunk < NX; chunk += 256) {
        float w = row[chunk + tid];
        bool p = (w != 0.0f);
        unsigned long long m = __ballot(p);
        int lp = (int)__popcll(m & ((1ull << ln) - 1ull));
        if (ln == 63) wave_tot[wv] = lp + (p ? 1 : 0);
        __syncthreads();
        int wbase = 0;
        #pragma unroll
        for (int i = 0; i < 4; ++i)
            if (i < wv) wbase += wave_tot[i];
        int tot = wave_tot[0] + wave_tot[1] + wave_tot[2] + wave_tot[3];
        if (p) {
            int o = base + wbase + lp;
            if (o < CAP) out[o] = make_int2(chunk + tid, __float_as_int(w));
        }
        __syncthreads();
        if (tid == 0) base += tot;
        __syncthreads();
    }
    // zero-pad remainder: col=0, val=0 contributes exactly 0
    for (int o = base + tid; o < CAP; o += 256) out[o] = make_int2(0, 0);
}

// --- Kernel 2: cooperative sequential recurrence, fence-free ---
__global__ void __launch_bounds__(TPB, 1) esn_kernel(
    const float* __restrict__ UT, const float* __restrict__ x0,
    const float* __restrict__ Win, const float* __restrict__ Wout,
    const int2* __restrict__ ell, float* __restrict__ xbuf,  // [2][NX]
    int* __restrict__ flags, float* __restrict__ Y)
{
    __shared__ __align__(16) float xl[NX];
    __shared__ float xnew_l[RPW];
    __shared__ float ul[NU];
    __shared__ float red[TPB / 64];

    const int tid = threadIdx.x;
    const int wg  = blockIdx.x;              // 0..63
    const int grp = tid >> 3;                // row group within WG (0..63)
    const int ln  = tid & 7;                 // lane within row group
    const int r   = wg * RPW + grp;          // global row this 8-thread group owns

    // contiguous per-thread slices -> int4/float4 loads (normal cached: static data)
    const float4* winrow = (const float4*)(Win + (size_t)r * NU + ln * UPT);
    const int4*   ellrow = (const int4*)  (ell + (size_t)r * CAP + ln * EPT);
    const float*  woutrow = Wout + (size_t)wg * NX;

    for (int t = 0; t < TSTEPS; ++t) {
        // ---- stage x_t into LDS ----
        if (t == 0) {
            const float4* xs4 = (const float4*)x0;
            float4* xl4 = (float4*)xl;
            #pragma unroll
            for (int i = tid; i < NX / 4; i += TPB) xl4[i] = xs4[i];
        } else {
            // coherent (sc1, L2-bypass) loads of the freshly published state
            const unsigned long long* xs8 =
                (const unsigned long long*)(xbuf + (size_t)(t & 1) * NX);
            float2* xl2 = (float2*)xl;
            #pragma unroll
            for (int j = 0; j < NX / 2 / TPB; ++j) {   // 4 iterations
                int i = tid + TPB * j;
                unsigned long long raw = __hip_atomic_load(
                    xs8 + i, __ATOMIC_RELAXED, __HIP_MEMORY_SCOPE_AGENT);
                union { unsigned long long u; float2 f; } c; c.u = raw;
                xl2[i] = c.f;
            }
        }
        if (tid < NU) ul[tid] = UT[(size_t)t * NU + tid];
        __syncthreads();

        // ---- pre[r] = Win[r,:] @ u + W[r,:] @ x (sparse ELL) ----
        float acc = 0.0f;
        const float* up = ul + ln * UPT;
        #pragma unroll
        for (int i = 0; i < UPT / 4; ++i) {
            float4 w = winrow[i];
            acc += w.x * up[4 * i] + w.y * up[4 * i + 1]
                 + w.z * up[4 * i + 2] + w.w * up[4 * i + 3];
        }
        #pragma unroll 4
        for (int i = 0; i < EPT / 2; ++i) {
            int4 cv = ellrow[i];   // two (col,val) pairs
            acc += __int_as_float(cv.y) * xl[cv.x]
                 + __int_as_float(cv.w) * xl[cv.z];
        }
        acc += __shfl_down(acc, 4, 8);
        acc += __shfl_down(acc, 2, 8);
        acc += __shfl_down(acc, 1, 8);
        if (ln == 0)
            xnew_l[grp] = 0.1f * xl[r] + 0.9f * tanhf(acc);
        __syncthreads();

        // ---- publish x_{t+1} (wave 0, coalesced sc1 stores) + arrive ----
        float* xdst = xbuf + (size_t)((t + 1) & 1) * NX + wg * RPW;
        if (tid < RPW) {   // RPW==64 -> exactly wave 0
            __hip_atomic_store(xdst + tid, xnew_l[tid],
                               __ATOMIC_RELAXED, __HIP_MEMORY_SCOPE_AGENT);
            asm volatile("s_waitcnt vmcnt(0)" ::: "memory");  // x at coherence point
        }
        if (tid == 0)
            __hip_atomic_store(flags + wg, t + 1,
                               __ATOMIC_RELAXED, __HIP_MEMORY_SCOPE_AGENT);

        // ---- readout Y[t-1] = Wout[wg] . x_t (hidden in barrier-wait window) ----
        if (t > 0) {
            float a = 0.0f;
            for (int i = tid; i < NX; i += TPB) a += woutrow[i] * xl[i];
            for (int off = 32; off; off >>= 1) a += __shfl_down(a, off, 64);
            if ((tid & 63) == 0) red[tid >> 6] = a;
            __syncthreads();
            if (tid == 0) {
                float s = 0.0f;
                #pragma unroll
                for (int i = 0; i < TPB / 64; ++i) s += red[i];
                Y[(size_t)(t - 1) * NY + wg] = s;
            }
        }

        // ---- wait: all WGs published step t+1 ----
        if (tid < 64) {
            int v;
            do {
                v = __hip_atomic_load(flags + tid, __ATOMIC_RELAXED,
                                      __HIP_MEMORY_SCOPE_AGENT);
            } while (__ballot(v < t + 1) != 0ull);
        }
        __syncthreads();
    }

    // ---- final readout: Y[T-1][wg] = Wout[wg] . x_T (coherent loads) ----
    {
        const float* xs = xbuf + (size_t)(TSTEPS & 1) * NX;   // TSTEPS even -> buf 0
        float a = 0.0f;
        for (int i = tid; i < NX; i += TPB) {
            float v = __hip_atomic_load(xs + i, __ATOMIC_RELAXED,
                                        __HIP_MEMORY_SCOPE_AGENT);
            a += woutrow[i] * v;
        }
        for (int off = 32; off; off >>= 1) a += __shfl_down(a, off, 64);
        if ((tid & 63) == 0) red[tid >> 6] = a;
        __syncthreads();
        if (tid == 0) {
            float s = 0.0f;
            #pragma unroll
            for (int i = 0; i < TPB / 64; ++i) s += red[i];
            Y[(size_t)(TSTEPS - 1) * NY + wg] = s;
        }
    }
}

extern "C" void kernel_launch(void* const* d_in, const int* in_sizes, int n_in,
                              void* d_out, int out_size, void* d_ws, size_t ws_size,
                              hipStream_t stream) {
    const float* UT   = (const float*)d_in[0];  // [T, NU]
    const float* x0   = (const float*)d_in[1];  // [NX]
    const float* Win  = (const float*)d_in[2];  // [NX, NU]
    const float* W    = (const float*)d_in[3];  // [NX, NX]
    const float* Wout = (const float*)d_in[4];  // [NY, NX]
    float* Y = (float*)d_out;                   // [T*NY]

    char* ws = (char*)d_ws;
    float* xbuf = (float*)ws;                               // 2*NX floats = 32 KB
    int2*  ell  = (int2*)(ws + 32768);                      // NX*CAP*8 = 11,534,336 B
    int*   flags = (int*)(ws + 32768 + (size_t)NX * CAP * 8);  // 64 ints

    build_ell_kernel<<<dim3(NX), dim3(256), 0, stream>>>(W, ell, flags);

    void* args[] = { (void*)&UT, (void*)&x0, (void*)&Win, (void*)&Wout,
                     (void*)&ell, (void*)&xbuf, (void*)&flags, (void*)&Y };
    hipLaunchCooperativeKernel((const void*)esn_kernel, dim3(WGS), dim3(TPB),
                               args, 0, stream);
}

// Round 4
// 20979.544 us; speedup vs baseline: 4.6303x; 1.1862x over previous
//
#include <hip/hip_runtime.h>
#include <math.h>

// ESN forward: x_{t+1} = 0.1*x_t + 0.9*tanh(W_in @ u_t + W @ x_t); y_t = Wout @ x_{t+1}
// W sparse (5%) -> padded ELL in ws. 64 cooperative WGs, fence-free.
// R4: single-round-trip exchange. State published as packed (epoch<<32|fbits)
// 8-byte relaxed agent atomics; readers poll the DATA itself (no flag array,
// no second load). 2-deep parity double buffer makes overwrite safe.

#define NX 4096
#define NU 128
#define NY 64
#define TSTEPS 4096
#define CAP 352            // padded nnz per row (mean 204.8, sd 13.9)
#define WGS 64
#define TPB 512
#define RPW (NX / WGS)     // 64 rows per workgroup
#define TPR (TPB / RPW)    // 8 threads per row
#define EPT (CAP / TPR)    // 44 ELL entries per thread (contiguous chunk)
#define UPT (NU / TPR)     // 16 W_in entries per thread (contiguous chunk)
#define XW  (NX / TPB)     // 8 packed words polled per thread

typedef unsigned long long u64;

// --- Kernel 1: deterministic dense->ELL compaction, one block per row ---
__global__ void build_ell_kernel(const float* __restrict__ W, int2* __restrict__ ell) {
    const int r = blockIdx.x;
    const int tid = threadIdx.x;
    const int wv = tid >> 6, ln = tid & 63;
    __shared__ int wave_tot[4];
    __shared__ int base;
    if (tid == 0) base = 0;
    __syncthreads();
    const float* row = W + (size_t)r * NX;
    int2* out = ell + (size_t)r * CAP;
    for (int chunk = 0; chunk < NX; chunk += 256) {
        float w = row[chunk + tid];
        bool p = (w != 0.0f);
        unsigned long long m = __ballot(p);
        int lp = (int)__popcll(m & ((1ull << ln) - 1ull));
        if (ln == 63) wave_tot[wv] = lp + (p ? 1 : 0);
        __syncthreads();
        int wbase = 0;
        #pragma unroll
        for (int i = 0; i < 4; ++i)
            if (i < wv) wbase += wave_tot[i];
        int tot = wave_tot[0] + wave_tot[1] + wave_tot[2] + wave_tot[3];
        if (p) {
            int o = base + wbase + lp;
            if (o < CAP) out[o] = make_int2(chunk + tid, __float_as_int(w));
        }
        __syncthreads();
        if (tid == 0) base += tot;
        __syncthreads();
    }
    // zero-pad remainder: col=0, val=0 contributes exactly 0
    for (int o = base + tid; o < CAP; o += 256) out[o] = make_int2(0, 0);
}

// --- Kernel 2: cooperative sequential recurrence, data-is-the-flag ---
__global__ void __launch_bounds__(TPB, 1) esn_kernel(
    const float* __restrict__ UT, const float* __restrict__ x0,
    const float* __restrict__ Win, const float* __restrict__ Wout,
    const int2* __restrict__ ell, u64* __restrict__ xbuf,  // [2][NX] packed
    float* __restrict__ Y)
{
    __shared__ __align__(16) float xl[2][NX];
    __shared__ float xnew_l[RPW];
    __shared__ float red[TPB / 64];

    const int tid = threadIdx.x;
    const int wg  = blockIdx.x;              // 0..63
    const int grp = tid >> 3;                // row group within WG (0..63)
    const int ln  = tid & 7;                 // lane within row group
    const int r   = wg * RPW + grp;          // global row this 8-thread group owns

    // contiguous per-thread slices -> int4/float4 loads (static, stays cached)
    const float4* winrow = (const float4*)(Win + (size_t)r * NU + ln * UPT);
    const int4*   ellrow = (const int4*)  (ell + (size_t)r * CAP + ln * EPT);
    const float*  woutrow = Wout + (size_t)wg * NX;

    for (int t = 0; t < TSTEPS; ++t) {
        float* xc = xl[t & 1];

        // ---- x-independent partial: acc = Win[r,:] @ u_t (L1/L2-cached global) ----
        float acc = 0.0f;
        {
            const float4* u4 = (const float4*)(UT + (size_t)t * NU + ln * UPT);
            #pragma unroll
            for (int i = 0; i < UPT / 4; ++i) {
                float4 w = winrow[i], u = u4[i];
                acc += w.x * u.x + w.y * u.y + w.z * u.z + w.w * u.w;
            }
        }

        // ---- stage x_t into LDS: poll packed (epoch|value) words directly ----
        if (t == 0) {
            const float4* xs4 = (const float4*)x0;
            float4* xl4 = (float4*)xc;
            #pragma unroll
            for (int i = tid; i < NX / 4; i += TPB) xl4[i] = xs4[i];
        } else {
            const u64* xs = xbuf + (size_t)(t & 1) * NX;
            u64 v[XW];
            bool ok;
            do {
                ok = true;
                #pragma unroll
                for (int j = 0; j < XW; ++j)
                    v[j] = __hip_atomic_load(xs + tid + TPB * j,
                                             __ATOMIC_RELAXED, __HIP_MEMORY_SCOPE_AGENT);
                #pragma unroll
                for (int j = 0; j < XW; ++j)
                    ok &= ((unsigned)(v[j] >> 32) == (unsigned)t);
            } while (!ok);
            #pragma unroll
            for (int j = 0; j < XW; ++j)
                xc[tid + TPB * j] = __uint_as_float((unsigned)v[j]);
        }
        __syncthreads();

        // ---- acc += W[r,:] @ x_t (sparse ELL gather from LDS) ----
        #pragma unroll 4
        for (int i = 0; i < EPT / 2; ++i) {
            int4 cv = ellrow[i];   // two (col,val) pairs
            acc += __int_as_float(cv.y) * xc[cv.x]
                 + __int_as_float(cv.w) * xc[cv.z];
        }
        acc += __shfl_down(acc, 4, 8);
        acc += __shfl_down(acc, 2, 8);
        acc += __shfl_down(acc, 1, 8);
        if (ln == 0)
            xnew_l[grp] = 0.1f * xc[r] + 0.9f * tanhf(acc);
        __syncthreads();

        // ---- publish x_{t+1}: one packed 8B atomic per row (wave 0) ----
        if (tid < RPW) {
            u64 packed = ((u64)(unsigned)(t + 1) << 32)
                       | (u64)__float_as_uint(xnew_l[tid]);
            __hip_atomic_store(xbuf + (size_t)((t + 1) & 1) * NX + wg * RPW + tid,
                               packed, __ATOMIC_RELAXED, __HIP_MEMORY_SCOPE_AGENT);
        }

        // ---- readout Y[t-1] = Wout[wg] . x_t (off the critical path) ----
        if (t > 0) {
            float a = 0.0f;
            for (int i = tid; i < NX; i += TPB) a += woutrow[i] * xc[i];
            for (int off = 32; off; off >>= 1) a += __shfl_down(a, off, 64);
            if ((tid & 63) == 0) red[tid >> 6] = a;
            __syncthreads();
            if (tid == 0) {
                float s = 0.0f;
                #pragma unroll
                for (int i = 0; i < TPB / 64; ++i) s += red[i];
                Y[(size_t)(t - 1) * NY + wg] = s;
            }
        }
    }

    // ---- final: poll x_T (epoch TSTEPS, buffer 0), then Y[T-1] ----
    {
        float* xc = xl[0];
        const u64* xs = xbuf + (size_t)(TSTEPS & 1) * NX;
        u64 v[XW];
        bool ok;
        do {
            ok = true;
            #pragma unroll
            for (int j = 0; j < XW; ++j)
                v[j] = __hip_atomic_load(xs + tid + TPB * j,
                                         __ATOMIC_RELAXED, __HIP_MEMORY_SCOPE_AGENT);
            #pragma unroll
            for (int j = 0; j < XW; ++j)
                ok &= ((unsigned)(v[j] >> 32) == (unsigned)TSTEPS);
        } while (!ok);
        #pragma unroll
        for (int j = 0; j < XW; ++j)
            xc[tid + TPB * j] = __uint_as_float((unsigned)v[j]);
        __syncthreads();

        float a = 0.0f;
        for (int i = tid; i < NX; i += TPB) a += woutrow[i] * xc[i];
        for (int off = 32; off; off >>= 1) a += __shfl_down(a, off, 64);
        if ((tid & 63) == 0) red[tid >> 6] = a;
        __syncthreads();
        if (tid == 0) {
            float s = 0.0f;
            #pragma unroll
            for (int i = 0; i < TPB / 64; ++i) s += red[i];
            Y[(size_t)(TSTEPS - 1) * NY + wg] = s;
        }
    }
}

extern "C" void kernel_launch(void* const* d_in, const int* in_sizes, int n_in,
                              void* d_out, int out_size, void* d_ws, size_t ws_size,
                              hipStream_t stream) {
    const float* UT   = (const float*)d_in[0];  // [T, NU]
    const float* x0   = (const float*)d_in[1];  // [NX]
    const float* Win  = (const float*)d_in[2];  // [NX, NU]
    const float* W    = (const float*)d_in[3];  // [NX, NX]
    const float* Wout = (const float*)d_in[4];  // [NY, NX]
    float* Y = (float*)d_out;                   // [T*NY]

    char* ws = (char*)d_ws;
    u64*  xbuf = (u64*)ws;                      // 2*NX packed words = 64 KB
    int2* ell  = (int2*)(ws + 65536);           // NX*CAP*8 = 11,534,336 B

    build_ell_kernel<<<dim3(NX), dim3(256), 0, stream>>>(W, ell);

    void* args[] = { (void*)&UT, (void*)&x0, (void*)&Win, (void*)&Wout,
                     (void*)&ell, (void*)&xbuf, (void*)&Y };
    hipLaunchCooperativeKernel((const void*)esn_kernel, dim3(WGS), dim3(TPB),
                               args, 0, stream);
}